// Round 4
// baseline (356.275 us; speedup 1.0000x reference)
//
#include <hip/hip_runtime.h>

// CvT block, MI355X bf16-MFMA implementation.
// B=32, C=128, L=32 (seq=1024), H=8, DK=64, HD=512, NLAYER=4.
// R4: GEMM epilogues restructured — MFMA orientation chosen so the
// memory-contiguous output axis is the m (register) axis; 4 consecutive
// values pack into 8B (bf16, v_perm+RNE) or 16B (f32) stores. Kills the
// 2B/4B store-scatter that made qkv_gemm TA-pipe bound (122us, all idle).

#define NB   32
#define NH   8
#define SEQ  1024
#define DKH  64
#define HDIM 512
#define CIN  128

// 0.125 * log2(e): folded into Wq and bias so scores are in exp2 domain.
#define SCL 0.18033688011112042f

typedef __bf16 bf16x8 __attribute__((ext_vector_type(8)));
typedef float floatx4 __attribute__((ext_vector_type(4)));
typedef unsigned short u16x8 __attribute__((ext_vector_type(8)));

__device__ __forceinline__ unsigned short f2bf(float f) {
    union { float f; unsigned int u; } c; c.f = f;
    unsigned int u = c.u;
    return (unsigned short)((u + 0x7fffu + ((u >> 16) & 1u)) >> 16); // RNE
}
__device__ __forceinline__ bf16x8 ldfrag(const unsigned short* p) {
    u16x8 v = *reinterpret_cast<const u16x8*>(p);
    return __builtin_bit_cast(bf16x8, v);
}
__device__ __forceinline__ float bfhi(unsigned int u) {  // low short -> f32
    return __builtin_bit_cast(float, u << 16);
}
__device__ __forceinline__ float bflo(unsigned int u) {  // high short -> f32
    return __builtin_bit_cast(float, u & 0xFFFF0000u);
}
// pack two f32 -> two RNE bf16; 'a' lands in the LOW short.
__device__ __forceinline__ unsigned int pkbf(float a, float b) {
    unsigned int ua = __builtin_bit_cast(unsigned int, a);
    unsigned int ub = __builtin_bit_cast(unsigned int, b);
    ua += 0x7fffu + ((ua >> 16) & 1u);
    ub += 0x7fffu + ((ub >> 16) & 1u);
    return __builtin_amdgcn_perm(ub, ua, 0x07060302u);
}

// ---------------- prep: weights + swizzled bias ----------------
// blocks [0, 32768): biasC in MFMA C-fragment order:
//   biasC[((h*64+ti)*64+tjv)*256 + lane] as ushort4 over r, where the C value
//   for (row 16ti+4q+r, virtual col 16s+n) is bias[i][64*(tjv>>2)+4n+(tjv&3)]
//   (key-permuted: virtual col 16s+n <-> actual key 4n+s within each 64-tile).
// blocks [32768, 33792): weight cast; Wq scaled by SCL (exp2 domain).
__global__ __launch_bounds__(256) void prep_wb(const float* __restrict__ Wq,
                                               const float* __restrict__ Wk,
                                               const float* __restrict__ Wv,
                                               const float* __restrict__ W0,
                                               const float* __restrict__ R,
                                               unsigned short* __restrict__ wqkvb,
                                               unsigned short* __restrict__ w0b,
                                               unsigned short* __restrict__ biasC) {
    if (blockIdx.x < 32768) {
        int gidx = blockIdx.x * 256 + threadIdx.x;       // [0, 8388608)
        int lane = gidx & 255, tjv = (gidx >> 8) & 63, ti = (gidx >> 14) & 63, h = gidx >> 20;
        int q = lane >> 4, n = lane & 15;
        int j = 64 * (tjv >> 2) + 4 * n + (tjv & 3);
        int jx = j >> 5, jy = j & 31;
        const float* Rh = R + (h << 10);
        unsigned short v[4];
        for (int r = 0; r < 4; ++r) {
            int i = 16 * ti + 4 * q + r;
            int ix = i >> 5, iy = i & 31;
            float val = Rh[(((ix - jx) & 31) << 5) + ((iy - jy) & 31)] * SCL;
            v[r] = f2bf(val);
        }
        unsigned long long pk = (unsigned long long)v[0] | ((unsigned long long)v[1] << 16) |
                                ((unsigned long long)v[2] << 32) | ((unsigned long long)v[3] << 48);
        *(unsigned long long*)&biasC[(size_t)gidx * 4] = pk;
    } else {
        int idx = (blockIdx.x - 32768) * 256 + threadIdx.x;  // [0, 262144)
        if (idx < 196608) {
            int row = idx >> 7;
            float v;
            if (row < 512)       v = Wq[idx] * SCL;
            else if (row < 1024) v = Wk[idx - 65536];
            else                 v = Wv[idx - 131072];
            wqkvb[idx] = f2bf(v);
        } else {
            int j = idx - 196608;
            w0b[j] = f2bf(W0[j]);
        }
    }
}

// xt[b][pos][c] = x[b][c][pos] * inv_layer, bf16.
__global__ __launch_bounds__(256) void prep_xt(const float* __restrict__ x,
                                               unsigned short* __restrict__ xt) {
    __shared__ float lds[64 * 65];
    int b = blockIdx.x, c0 = blockIdx.y * 64, p0 = blockIdx.z * 64;
    int t = threadIdx.x, tr = t >> 6, tc = t & 63;
    const float inv_layer = 0.44721359549995793f;  // 1/sqrt(5)
    for (int rr = 0; rr < 16; ++rr) {
        int cl = rr * 4 + tr;
        lds[cl * 65 + tc] = x[(b * CIN + c0 + cl) * SEQ + p0 + tc];
    }
    __syncthreads();
    for (int rr = 0; rr < 16; ++rr) {
        int pl = rr * 4 + tr;
        xt[(b * SEQ + p0 + pl) * CIN + c0 + tc] = f2bf(lds[tc * 65 + pl] * inv_layer);
    }
}

// ---------------- fused QKV projection ----------------
// y in [0,16): Q/K, orientation B: A = wqkv rows (m=wrow), B = xt (n=pos).
//   D row = wrow (d contiguous in regs) -> 8B packed stores to (b,h,pos,d).
// y in [16,24): V, orientation A: A = xt (m=pos), B = Wv rows (n=vrow).
//   D row = pos (contiguous in regs)   -> 8B packed stores to (b,h,d,pos).
__global__ __launch_bounds__(256) void qkv_gemm(const unsigned short* __restrict__ xt,
                                                const unsigned short* __restrict__ wqkv,
                                                unsigned short* __restrict__ Qt,
                                                unsigned short* __restrict__ Kt,
                                                unsigned short* __restrict__ Vt) {
    int b = blockIdx.x, y = blockIdx.y, zt = blockIdx.z;
    int tid = threadIdx.x, wave = tid >> 6, lane = tid & 63, q = lane >> 4, n = lane & 15;
    floatx4 acc[4];
    for (int s = 0; s < 4; ++s) acc[s] = (floatx4){0.f, 0.f, 0.f, 0.f};
    if (y < 16) {
        int wrow0 = y * 64 + wave * 16;   // 16 weight rows per wave (one head each)
        int pos0 = zt * 64;
        const unsigned short* wrowp = wqkv + (wrow0 + n) * CIN;
        for (int kc = 0; kc < 4; ++kc) {
            bf16x8 a = ldfrag(wrowp + kc * 32 + q * 8);
            for (int s = 0; s < 4; ++s) {
                bf16x8 bx = ldfrag(xt + (b * SEQ + pos0 + 16 * s + n) * CIN + kc * 32 + q * 8);
                acc[s] = __builtin_amdgcn_mfma_f32_16x16x32_bf16(a, bx, acc[s], 0, 0, 0);
            }
        }
        int d0 = (wrow0 & 63) + 4 * q;
        unsigned short* dst = (y < 8) ? Qt : Kt;
        int h = (y < 8) ? (wrow0 >> 6) : ((wrow0 >> 6) - 8);
        for (int s = 0; s < 4; ++s) {
            uint2 pk;
            pk.x = pkbf(acc[s][0], acc[s][1]);
            pk.y = pkbf(acc[s][2], acc[s][3]);
            int pos = pos0 + 16 * s + n;
            *(uint2*)&dst[((size_t)(b * NH + h) * SEQ + pos) * DKH + d0] = pk;
        }
    } else {
        int pos0 = zt * 64 + wave * 16;
        int vrow0 = (y - 16) * 64;
        const unsigned short* xrow = xt + (b * SEQ + pos0 + n) * CIN;
        for (int kc = 0; kc < 4; ++kc) {
            bf16x8 a = ldfrag(xrow + kc * 32 + q * 8);
            for (int s = 0; s < 4; ++s) {
                bf16x8 bw = ldfrag(wqkv + (1024 + vrow0 + 16 * s + n) * CIN + kc * 32 + q * 8);
                acc[s] = __builtin_amdgcn_mfma_f32_16x16x32_bf16(a, bw, acc[s], 0, 0, 0);
            }
        }
        int p0q = pos0 + 4 * q;
        for (int s = 0; s < 4; ++s) {
            int vrow = vrow0 + 16 * s + n;
            int h = vrow >> 6, d = vrow & 63;
            uint2 pk;
            pk.x = pkbf(acc[s][0], acc[s][1]);
            pk.y = pkbf(acc[s][2], acc[s][3]);
            *(uint2*)&Vt[((size_t)(b * NH + h) * DKH + d) * SEQ + p0q] = pk;
        }
    }
}

// ---------------- attention (no online-softmax bookkeeping) ----------------
// WG = 128 queries (4 waves x 32); key tiles of 64; grid swizzle: gid&255 =
// (b,h) so each XCD sees one head (L2-resident bias/K/V).
__global__ __launch_bounds__(256, 3) void attn_kernel(const unsigned short* __restrict__ Qt,
                                                      const unsigned short* __restrict__ Kt,
                                                      const unsigned short* __restrict__ Vt,
                                                      const unsigned short* __restrict__ biasC,
                                                      unsigned short* __restrict__ att) {
    __shared__ alignas(16) unsigned short lds_k[64 * 72];    // row = perm'd key slot
    __shared__ alignas(16) unsigned short lds_v[64 * 72];    // (d, j) natural
    __shared__ alignas(16) unsigned short lds_p[4][32 * 72]; // per-wave P (i, actual j)

    int gid = blockIdx.x;
    int bh = gid & 255, qb = gid >> 8;
    int b = bh >> 3, h = bh & 7;
    int tid = threadIdx.x, wave = tid >> 6, lane = tid & 63, q = lane >> 4, n = lane & 15;
    int i0 = qb * 128 + wave * 32;

    const unsigned short* qbase = Qt + (b * NH + h) * SEQ * DKH;
    const unsigned short* kbase = Kt + (b * NH + h) * SEQ * DKH;
    const unsigned short* vbase = Vt + (b * NH + h) * DKH * SEQ;
    const unsigned short* bCh = biasC + (size_t)h * 64 * 64 * 1024;

    bf16x8 aq[2][2];
    for (int mt = 0; mt < 2; ++mt)
        for (int c = 0; c < 2; ++c)
            aq[mt][c] = ldfrag(qbase + (i0 + mt * 16 + n) * DKH + c * 32 + q * 8);

    // all-ones B fragment for row-sum MFMA (l = P @ 1)
    u16x8 ones_u;
    for (int t = 0; t < 8; ++t) ones_u[t] = 0x3F80;
    bf16x8 vone = __builtin_bit_cast(bf16x8, ones_u);

    floatx4 o[2][4], acc_l[2];
    for (int mt = 0; mt < 2; ++mt) {
        acc_l[mt] = (floatx4){0.f, 0.f, 0.f, 0.f};
        for (int u = 0; u < 4; ++u) o[mt][u] = (floatx4){0.f, 0.f, 0.f, 0.f};
    }

    int srow = tid >> 2, sseg = tid & 3;                 // staging: 64 rows x 4 segs
    int krow = 16 * (srow & 3) + (srow >> 2);            // K row permutation sigma^-1
    unsigned short* pw = &lds_p[wave][0];
    int ti0 = i0 >> 4;

    for (int kt = 0; kt < 16; ++kt) {
        int j0 = kt * 64;
        __syncthreads();  // prior PV reads done before overwriting K/V tiles
        {
            const unsigned short* ks = kbase + (j0 + srow) * DKH + sseg * 16;
            u16x8 k0 = *(const u16x8*)ks;
            u16x8 k1 = *(const u16x8*)(ks + 8);
            *(u16x8*)&lds_k[krow * 72 + sseg * 16] = k0;
            *(u16x8*)&lds_k[krow * 72 + sseg * 16 + 8] = k1;
            const unsigned short* vs = vbase + srow * SEQ + j0 + sseg * 16;
            u16x8 v0 = *(const u16x8*)vs;
            u16x8 v1 = *(const u16x8*)(vs + 8);
            *(u16x8*)&lds_v[srow * 72 + sseg * 16] = v0;
            *(u16x8*)&lds_v[srow * 72 + sseg * 16 + 8] = v1;
        }
        __syncthreads();

        // S = Q K^T + bias (C-init); virtual col 16s+n = actual key 4n+s
        floatx4 sv[2][4];
        for (int mt = 0; mt < 2; ++mt)
            for (int s = 0; s < 4; ++s) {
                const unsigned int* bp = (const unsigned int*)
                    (bCh + ((size_t)((ti0 + mt) * 64 + 4 * kt + s) * 1024) + lane * 4);
                unsigned int b0 = bp[0], b1 = bp[1];
                sv[mt][s] = (floatx4){bfhi(b0), bflo(b0), bfhi(b1), bflo(b1)};
            }
        for (int s = 0; s < 4; ++s) {
            bf16x8 bk0 = ldfrag(&lds_k[(16 * s + n) * 72 + 0 + q * 8]);
            bf16x8 bk1 = ldfrag(&lds_k[(16 * s + n) * 72 + 32 + q * 8]);
            for (int mt = 0; mt < 2; ++mt) {
                sv[mt][s] = __builtin_amdgcn_mfma_f32_16x16x32_bf16(aq[mt][0], bk0, sv[mt][s], 0, 0, 0);
                sv[mt][s] = __builtin_amdgcn_mfma_f32_16x16x32_bf16(aq[mt][1], bk1, sv[mt][s], 0, 0, 0);
            }
        }

        // P = exp2(S); pack adjacent keys (4n..4n+3) via v_perm; store b64
        for (int mt = 0; mt < 2; ++mt)
            for (int r = 0; r < 4; ++r) {
                unsigned int p0 = __builtin_bit_cast(unsigned int, __builtin_amdgcn_exp2f(sv[mt][0][r]));
                unsigned int p1 = __builtin_bit_cast(unsigned int, __builtin_amdgcn_exp2f(sv[mt][1][r]));
                unsigned int p2 = __builtin_bit_cast(unsigned int, __builtin_amdgcn_exp2f(sv[mt][2][r]));
                unsigned int p3 = __builtin_bit_cast(unsigned int, __builtin_amdgcn_exp2f(sv[mt][3][r]));
                uint2 pk;
                pk.x = __builtin_amdgcn_perm(p1, p0, 0x07060302u);  // [hi(p0), hi(p1)]
                pk.y = __builtin_amdgcn_perm(p3, p2, 0x07060302u);  // [hi(p2), hi(p3)]
                *(uint2*)&pw[(mt * 16 + 4 * q + r) * 72 + 4 * n] = pk;
            }
        // no barrier: lds_p is per-wave (in-order DS ops within the wave)

        // O += P V ; l += P @ 1 (row sums on the MFMA pipe)
        bf16x8 ap[2][2];
        for (int mt = 0; mt < 2; ++mt)
            for (int c = 0; c < 2; ++c)
                ap[mt][c] = ldfrag(&pw[(mt * 16 + n) * 72 + c * 32 + q * 8]);
        for (int mt = 0; mt < 2; ++mt) {
            acc_l[mt] = __builtin_amdgcn_mfma_f32_16x16x32_bf16(ap[mt][0], vone, acc_l[mt], 0, 0, 0);
            acc_l[mt] = __builtin_amdgcn_mfma_f32_16x16x32_bf16(ap[mt][1], vone, acc_l[mt], 0, 0, 0);
        }
        for (int u = 0; u < 4; ++u) {
            bf16x8 bv0 = ldfrag(&lds_v[(16 * u + n) * 72 + 0 + q * 8]);
            bf16x8 bv1 = ldfrag(&lds_v[(16 * u + n) * 72 + 32 + q * 8]);
            for (int mt = 0; mt < 2; ++mt) {
                o[mt][u] = __builtin_amdgcn_mfma_f32_16x16x32_bf16(ap[mt][0], bv0, o[mt][u], 0, 0, 0);
                o[mt][u] = __builtin_amdgcn_mfma_f32_16x16x32_bf16(ap[mt][1], bv1, o[mt][u], 0, 0, 0);
            }
        }
    }

    for (int mt = 0; mt < 2; ++mt)
        for (int r = 0; r < 4; ++r) {
            float inv = 1.0f / acc_l[mt][r];
            int i = i0 + mt * 16 + 4 * q + r;
            for (int u = 0; u < 4; ++u)
                att[((size_t)b * SEQ + i) * HDIM + h * DKH + 16 * u + n] = f2bf(o[mt][u][r] * inv);
        }
}

// ---------------- output projection + residual ----------------
// Orientation m=pos: A = att rows (pos, hd), B = w0b rows (c, hd).
// D row = pos (contiguous in regs) -> float4 stores + float4 residual loads.
__global__ __launch_bounds__(256) void out_gemm(const unsigned short* __restrict__ att,
                                                const unsigned short* __restrict__ w0b,
                                                const float* __restrict__ x,
                                                float* __restrict__ out) {
    int b = blockIdx.x, ct = blockIdx.y, pt = blockIdx.z;
    int tid = threadIdx.x, wave = tid >> 6, lane = tid & 63, q = lane >> 4, n = lane & 15;
    int pos0 = pt * 64 + wave * 16;
    int c0 = ct * 64;
    const unsigned short* arow = att + ((size_t)b * SEQ + pos0 + n) * HDIM;
    floatx4 acc[4];
    for (int s = 0; s < 4; ++s) acc[s] = (floatx4){0.f, 0.f, 0.f, 0.f};
    for (int kc = 0; kc < 16; ++kc) {
        bf16x8 a = ldfrag(arow + kc * 32 + q * 8);
        for (int s = 0; s < 4; ++s) {
            bf16x8 bw = ldfrag(w0b + (c0 + 16 * s + n) * HDIM + kc * 32 + q * 8);
            acc[s] = __builtin_amdgcn_mfma_f32_16x16x32_bf16(a, bw, acc[s], 0, 0, 0);
        }
    }
    int p0q = pos0 + 4 * q;
    for (int s = 0; s < 4; ++s) {
        int c = c0 + 16 * s + n;
        size_t idx = ((size_t)b * CIN + c) * SEQ + p0q;
        floatx4 res = *(const floatx4*)&x[idx];
        floatx4 v = acc[s] + res;
        *(floatx4*)&out[idx] = v;
    }
}

// ---------------- launch ----------------
extern "C" void kernel_launch(void* const* d_in, const int* in_sizes, int n_in,
                              void* d_out, int out_size, void* d_ws, size_t ws_size,
                              hipStream_t stream) {
    const float* x  = (const float*)d_in[0];
    const float* Wq = (const float*)d_in[1];
    const float* Wk = (const float*)d_in[2];
    const float* Wv = (const float*)d_in[3];
    const float* R  = (const float*)d_in[4];
    const float* W0 = (const float*)d_in[5];
    float* out = (float*)d_out;

    char* ws = (char*)d_ws;
    size_t off = 0;
    unsigned short* Qt    = (unsigned short*)(ws + off); off += (size_t)NB * NH * SEQ * DKH * 2;
    unsigned short* Kt    = (unsigned short*)(ws + off); off += (size_t)NB * NH * SEQ * DKH * 2;
    unsigned short* Vt    = (unsigned short*)(ws + off); off += (size_t)NB * NH * SEQ * DKH * 2;
    unsigned short* att   = (unsigned short*)(ws + off); off += (size_t)NB * SEQ * HDIM * 2;
    unsigned short* xt    = (unsigned short*)(ws + off); off += (size_t)NB * SEQ * CIN * 2;
    unsigned short* wqkvb = (unsigned short*)(ws + off); off += (size_t)1536 * 128 * 2;
    unsigned short* w0b   = (unsigned short*)(ws + off); off += (size_t)128 * 512 * 2;
    unsigned short* biasC = (unsigned short*)(ws + off); off += (size_t)NH * SEQ * SEQ * 2;
    (void)ws_size; (void)in_sizes; (void)n_in; (void)out_size;

    prep_wb<<<33792, 256, 0, stream>>>(Wq, Wk, Wv, W0, R, wqkvb, w0b, biasC);
    prep_xt<<<dim3(NB, 2, 16), 256, 0, stream>>>(x, xt);
    qkv_gemm<<<dim3(NB, 24, 16), 256, 0, stream>>>(xt, wqkvb, Qt, Kt, Vt);
    attn_kernel<<<NB * NH * 8, 256, 0, stream>>>(Qt, Kt, Vt, biasC, att);
    out_gemm<<<dim3(NB, 2, 16), 256, 0, stream>>>(att, w0b, x, out);
}

// Round 5
// 277.678 us; speedup vs baseline: 1.2831x; 1.2831x over previous
//
#include <hip/hip_runtime.h>

// CvT block, MI355X bf16-MFMA implementation.
// B=32, C=128, L=32 (seq=1024), H=8, DK=64, HD=512, NLAYER=4.
// R5: qkv_gemm/out_gemm were dependent-load-latency bound (VGPR=40, 20
// serialized 16-segment gathers/wave, all pipes <10%). Fix: (a) operands
// stored in MFMA fragment order -> each fragment load is one contiguous
// 1KB wave-load; (b) loads explicitly hoisted into register arrays
// (launch_bounds(256,4), ~110 VGPR) -> MLP 20, one latency per wave.

#define NB   32
#define NH   8
#define SEQ  1024
#define DKH  64
#define HDIM 512
#define CIN  128

// 0.125 * log2(e): folded into Wq and bias so scores are in exp2 domain.
#define SCL 0.18033688011112042f

typedef __bf16 bf16x8 __attribute__((ext_vector_type(8)));
typedef float floatx4 __attribute__((ext_vector_type(4)));
typedef unsigned short u16x8 __attribute__((ext_vector_type(8)));

__device__ __forceinline__ unsigned short f2bf(float f) {
    union { float f; unsigned int u; } c; c.f = f;
    unsigned int u = c.u;
    return (unsigned short)((u + 0x7fffu + ((u >> 16) & 1u)) >> 16); // RNE
}
__device__ __forceinline__ bf16x8 ldfrag(const unsigned short* p) {
    u16x8 v = *reinterpret_cast<const u16x8*>(p);
    return __builtin_bit_cast(bf16x8, v);
}
__device__ __forceinline__ float bfhi(unsigned int u) {  // low short -> f32
    return __builtin_bit_cast(float, u << 16);
}
__device__ __forceinline__ float bflo(unsigned int u) {  // high short -> f32
    return __builtin_bit_cast(float, u & 0xFFFF0000u);
}
// pack two f32 -> two RNE bf16; 'a' lands in the LOW short.
__device__ __forceinline__ unsigned int pkbf(float a, float b) {
    unsigned int ua = __builtin_bit_cast(unsigned int, a);
    unsigned int ub = __builtin_bit_cast(unsigned int, b);
    ua += 0x7fffu + ((ua >> 16) & 1u);
    ub += 0x7fffu + ((ub >> 16) & 1u);
    return __builtin_amdgcn_perm(ub, ua, 0x07060302u);
}

// Fragment-order storage: block(tile,kc) holds 16 rows x 32 k, flattened as
// [lane=q*16+n][j=0..7] <-> element (row=n, k=q*8+j). A wave's fragment load
// = base + lane*8 elems = contiguous 1KB.

// ---------------- prep: weights + swizzled bias ----------------
__global__ __launch_bounds__(256) void prep_wb(const float* __restrict__ Wq,
                                               const float* __restrict__ Wk,
                                               const float* __restrict__ Wv,
                                               const float* __restrict__ W0,
                                               const float* __restrict__ R,
                                               unsigned short* __restrict__ w2,
                                               unsigned short* __restrict__ w0f,
                                               unsigned short* __restrict__ biasC) {
    if (blockIdx.x < 32768) {
        // biasC in MFMA C-fragment order (key-permuted; see R3 comment)
        int gidx = blockIdx.x * 256 + threadIdx.x;       // [0, 8388608)
        int lane = gidx & 255, tjv = (gidx >> 8) & 63, ti = (gidx >> 14) & 63, h = gidx >> 20;
        int q = lane >> 4, n = lane & 15;
        int j = 64 * (tjv >> 2) + 4 * n + (tjv & 3);
        int jx = j >> 5, jy = j & 31;
        const float* Rh = R + (h << 10);
        unsigned short v[4];
        for (int r = 0; r < 4; ++r) {
            int i = 16 * ti + 4 * q + r;
            int ix = i >> 5, iy = i & 31;
            float val = Rh[(((ix - jx) & 31) << 5) + ((iy - jy) & 31)] * SCL;
            v[r] = f2bf(val);
        }
        unsigned long long pk = (unsigned long long)v[0] | ((unsigned long long)v[1] << 16) |
                                ((unsigned long long)v[2] << 32) | ((unsigned long long)v[3] << 48);
        *(unsigned long long*)&biasC[(size_t)gidx * 4] = pk;
    } else {
        int idx = (blockIdx.x - 32768) * 256 + threadIdx.x;  // [0, 262144)
        if (idx < 196608) {
            // wqkv rows 0-511 Wq*SCL, 512-1023 Wk, 1024-1535 Wv -> frag order
            int row = idx >> 7, col = idx & 127;
            float v;
            if (row < 512)       v = Wq[idx] * SCL;
            else if (row < 1024) v = Wk[idx - 65536];
            else                 v = Wv[idx - 131072];
            int rt = row >> 4, nr = row & 15, kc = col >> 5, qc = (col & 31) >> 3, jc = col & 7;
            w2[((rt * 4 + kc) * 512) + (qc * 16 + nr) * 8 + jc] = f2bf(v);
        } else {
            // W0 (c, hd) -> frag order over (ct=c/16, kcA=hd/32)
            int idx2 = idx - 196608;
            int row = idx2 >> 9, col = idx2 & 511;
            int rt = row >> 4, nr = row & 15, kcA = col >> 5, qc = (col & 31) >> 3, jc = col & 7;
            w0f[((rt * 16 + kcA) * 512) + (qc * 16 + nr) * 8 + jc] = f2bf(W0[idx2]);
        }
    }
}

// xt2: x transposed+scaled, in B/A fragment order over (b, pt=pos/16, kc=c/32).
__global__ __launch_bounds__(256) void prep_xt(const float* __restrict__ x,
                                               unsigned short* __restrict__ xt2) {
    __shared__ float lds[64 * 65];
    int b = blockIdx.x, c0 = blockIdx.y * 64, p0 = blockIdx.z * 64;
    int t = threadIdx.x, tr = t >> 6, tc = t & 63;
    const float inv_layer = 0.44721359549995793f;  // 1/sqrt(5)
    for (int rr = 0; rr < 16; ++rr) {
        int cl = rr * 4 + tr;
        lds[cl * 65 + tc] = x[(b * CIN + c0 + cl) * SEQ + p0 + tc];
    }
    __syncthreads();
    for (int rr = 0; rr < 16; ++rr) {
        int pl = rr * 4 + tr;
        int pos = p0 + pl, c = c0 + tc;
        int pt = pos >> 4, np = pos & 15, kc = c >> 5, qc = (c & 31) >> 3, jc = c & 7;
        xt2[((size_t)((b * 64 + pt) * 4 + kc) * 512) + (qc * 16 + np) * 8 + jc] =
            f2bf(lds[tc * 65 + pl] * inv_layer);
    }
}

// ---------------- fused QKV projection ----------------
// y in [0,16): Q/K, A = wqkv rows (m=wrow), B = xt (n=pos). D row = wrow ->
//   d contiguous in regs -> 8B packed stores to (b,h,pos,d).
// y in [16,24): V, A = xt (m=pos), B = Wv rows (n=vrow). D row = pos ->
//   8B packed stores to (b,h,d,pos).
__global__ __launch_bounds__(256, 4) void qkv_gemm(const unsigned short* __restrict__ xt2,
                                                   const unsigned short* __restrict__ w2,
                                                   unsigned short* __restrict__ Qt,
                                                   unsigned short* __restrict__ Kt,
                                                   unsigned short* __restrict__ Vt) {
    int b = blockIdx.x, y = blockIdx.y, zt = blockIdx.z;
    int tid = threadIdx.x, wave = tid >> 6, lane = tid & 63, q = lane >> 4, n = lane & 15;
    floatx4 acc[4];
    for (int s = 0; s < 4; ++s) acc[s] = (floatx4){0.f, 0.f, 0.f, 0.f};
    bf16x8 af[4], bfr[4][4];
    if (y < 16) {
        int rt = y * 4 + wave;                       // wrow tile
        const unsigned short* wbase = w2 + (size_t)rt * 4 * 512 + lane * 8;
        const unsigned short* xbase = xt2 + (size_t)(b * 64 + zt * 4) * 4 * 512 + lane * 8;
        for (int kc = 0; kc < 4; ++kc) af[kc] = ldfrag(wbase + kc * 512);
        for (int s = 0; s < 4; ++s)
            for (int kc = 0; kc < 4; ++kc) bfr[s][kc] = ldfrag(xbase + (s * 4 + kc) * 512);
        for (int kc = 0; kc < 4; ++kc)
            for (int s = 0; s < 4; ++s)
                acc[s] = __builtin_amdgcn_mfma_f32_16x16x32_bf16(af[kc], bfr[s][kc], acc[s], 0, 0, 0);
        int wrow0 = y * 64 + wave * 16;
        int pos0 = zt * 64;
        int d0 = (wrow0 & 63) + 4 * q;
        unsigned short* dst = (y < 8) ? Qt : Kt;
        int h = (y < 8) ? (wrow0 >> 6) : ((wrow0 >> 6) - 8);
        for (int s = 0; s < 4; ++s) {
            uint2 pk;
            pk.x = pkbf(acc[s][0], acc[s][1]);
            pk.y = pkbf(acc[s][2], acc[s][3]);
            int pos = pos0 + 16 * s + n;
            *(uint2*)&dst[((size_t)(b * NH + h) * SEQ + pos) * DKH + d0] = pk;
        }
    } else {
        int pt = zt * 4 + wave;                      // pos tile
        const unsigned short* xbase = xt2 + (size_t)((b * 64 + pt) * 4) * 512 + lane * 8;
        int rtv0 = 64 + (y - 16) * 4;                // V wrow tiles start at row 1024
        const unsigned short* wbase = w2 + (size_t)rtv0 * 4 * 512 + lane * 8;
        for (int kc = 0; kc < 4; ++kc) af[kc] = ldfrag(xbase + kc * 512);
        for (int s = 0; s < 4; ++s)
            for (int kc = 0; kc < 4; ++kc) bfr[s][kc] = ldfrag(wbase + (s * 4 + kc) * 512);
        for (int kc = 0; kc < 4; ++kc)
            for (int s = 0; s < 4; ++s)
                acc[s] = __builtin_amdgcn_mfma_f32_16x16x32_bf16(af[kc], bfr[s][kc], acc[s], 0, 0, 0);
        int pos0 = zt * 64 + wave * 16;
        int vrow0 = (y - 16) * 64;
        int p0q = pos0 + 4 * q;
        for (int s = 0; s < 4; ++s) {
            int vrow = vrow0 + 16 * s + n;
            int h = vrow >> 6, d = vrow & 63;
            uint2 pk;
            pk.x = pkbf(acc[s][0], acc[s][1]);
            pk.y = pkbf(acc[s][2], acc[s][3]);
            *(uint2*)&Vt[((size_t)(b * NH + h) * DKH + d) * SEQ + p0q] = pk;
        }
    }
}

// ---------------- attention (no online-softmax bookkeeping) ----------------
// WG = 128 queries (4 waves x 32); key tiles of 64; grid swizzle: gid&255 =
// (b,h) so each XCD sees one head (L2-resident bias/K/V).
// Output att2 in A-fragment order over (b, pt=pos/16, kcA=hd/32).
__global__ __launch_bounds__(256, 3) void attn_kernel(const unsigned short* __restrict__ Qt,
                                                      const unsigned short* __restrict__ Kt,
                                                      const unsigned short* __restrict__ Vt,
                                                      const unsigned short* __restrict__ biasC,
                                                      unsigned short* __restrict__ att2) {
    __shared__ alignas(16) unsigned short lds_k[64 * 72];    // row = perm'd key slot
    __shared__ alignas(16) unsigned short lds_v[64 * 72];    // (d, j) natural
    __shared__ alignas(16) unsigned short lds_p[4][32 * 72]; // per-wave P (i, actual j)

    int gid = blockIdx.x;
    int bh = gid & 255, qb = gid >> 8;
    int b = bh >> 3, h = bh & 7;
    int tid = threadIdx.x, wave = tid >> 6, lane = tid & 63, q = lane >> 4, n = lane & 15;
    int i0 = qb * 128 + wave * 32;

    const unsigned short* qbase = Qt + (b * NH + h) * SEQ * DKH;
    const unsigned short* kbase = Kt + (b * NH + h) * SEQ * DKH;
    const unsigned short* vbase = Vt + (b * NH + h) * DKH * SEQ;
    const unsigned short* bCh = biasC + (size_t)h * 64 * 64 * 1024;

    bf16x8 aq[2][2];
    for (int mt = 0; mt < 2; ++mt)
        for (int c = 0; c < 2; ++c)
            aq[mt][c] = ldfrag(qbase + (i0 + mt * 16 + n) * DKH + c * 32 + q * 8);

    // all-ones B fragment for row-sum MFMA (l = P @ 1)
    u16x8 ones_u;
    for (int t = 0; t < 8; ++t) ones_u[t] = 0x3F80;
    bf16x8 vone = __builtin_bit_cast(bf16x8, ones_u);

    floatx4 o[2][4], acc_l[2];
    for (int mt = 0; mt < 2; ++mt) {
        acc_l[mt] = (floatx4){0.f, 0.f, 0.f, 0.f};
        for (int u = 0; u < 4; ++u) o[mt][u] = (floatx4){0.f, 0.f, 0.f, 0.f};
    }

    int srow = tid >> 2, sseg = tid & 3;                 // staging: 64 rows x 4 segs
    int krow = 16 * (srow & 3) + (srow >> 2);            // K row permutation sigma^-1
    unsigned short* pw = &lds_p[wave][0];
    int ti0 = i0 >> 4;

    for (int kt = 0; kt < 16; ++kt) {
        int j0 = kt * 64;
        __syncthreads();  // prior PV reads done before overwriting K/V tiles
        {
            const unsigned short* ks = kbase + (j0 + srow) * DKH + sseg * 16;
            u16x8 k0 = *(const u16x8*)ks;
            u16x8 k1 = *(const u16x8*)(ks + 8);
            *(u16x8*)&lds_k[krow * 72 + sseg * 16] = k0;
            *(u16x8*)&lds_k[krow * 72 + sseg * 16 + 8] = k1;
            const unsigned short* vs = vbase + srow * SEQ + j0 + sseg * 16;
            u16x8 v0 = *(const u16x8*)vs;
            u16x8 v1 = *(const u16x8*)(vs + 8);
            *(u16x8*)&lds_v[srow * 72 + sseg * 16] = v0;
            *(u16x8*)&lds_v[srow * 72 + sseg * 16 + 8] = v1;
        }
        __syncthreads();

        // S = Q K^T + bias (C-init); virtual col 16s+n = actual key 4n+s
        floatx4 sv[2][4];
        for (int mt = 0; mt < 2; ++mt)
            for (int s = 0; s < 4; ++s) {
                const unsigned int* bp = (const unsigned int*)
                    (bCh + ((size_t)((ti0 + mt) * 64 + 4 * kt + s) * 1024) + lane * 4);
                unsigned int b0 = bp[0], b1 = bp[1];
                sv[mt][s] = (floatx4){bfhi(b0), bflo(b0), bfhi(b1), bflo(b1)};
            }
        for (int s = 0; s < 4; ++s) {
            bf16x8 bk0 = ldfrag(&lds_k[(16 * s + n) * 72 + 0 + q * 8]);
            bf16x8 bk1 = ldfrag(&lds_k[(16 * s + n) * 72 + 32 + q * 8]);
            for (int mt = 0; mt < 2; ++mt) {
                sv[mt][s] = __builtin_amdgcn_mfma_f32_16x16x32_bf16(aq[mt][0], bk0, sv[mt][s], 0, 0, 0);
                sv[mt][s] = __builtin_amdgcn_mfma_f32_16x16x32_bf16(aq[mt][1], bk1, sv[mt][s], 0, 0, 0);
            }
        }

        // P = exp2(S); pack adjacent keys (4n..4n+3) via v_perm; store b64
        for (int mt = 0; mt < 2; ++mt)
            for (int r = 0; r < 4; ++r) {
                unsigned int p0 = __builtin_bit_cast(unsigned int, __builtin_amdgcn_exp2f(sv[mt][0][r]));
                unsigned int p1 = __builtin_bit_cast(unsigned int, __builtin_amdgcn_exp2f(sv[mt][1][r]));
                unsigned int p2 = __builtin_bit_cast(unsigned int, __builtin_amdgcn_exp2f(sv[mt][2][r]));
                unsigned int p3 = __builtin_bit_cast(unsigned int, __builtin_amdgcn_exp2f(sv[mt][3][r]));
                uint2 pk;
                pk.x = __builtin_amdgcn_perm(p1, p0, 0x07060302u);  // [hi(p0), hi(p1)]
                pk.y = __builtin_amdgcn_perm(p3, p2, 0x07060302u);  // [hi(p2), hi(p3)]
                *(uint2*)&pw[(mt * 16 + 4 * q + r) * 72 + 4 * n] = pk;
            }
        // no barrier: lds_p is per-wave (in-order DS ops within the wave)

        // O += P V ; l += P @ 1 (row sums on the MFMA pipe)
        bf16x8 ap[2][2];
        for (int mt = 0; mt < 2; ++mt)
            for (int c = 0; c < 2; ++c)
                ap[mt][c] = ldfrag(&pw[(mt * 16 + n) * 72 + c * 32 + q * 8]);
        for (int mt = 0; mt < 2; ++mt) {
            acc_l[mt] = __builtin_amdgcn_mfma_f32_16x16x32_bf16(ap[mt][0], vone, acc_l[mt], 0, 0, 0);
            acc_l[mt] = __builtin_amdgcn_mfma_f32_16x16x32_bf16(ap[mt][1], vone, acc_l[mt], 0, 0, 0);
        }
        for (int u = 0; u < 4; ++u) {
            bf16x8 bv0 = ldfrag(&lds_v[(16 * u + n) * 72 + 0 + q * 8]);
            bf16x8 bv1 = ldfrag(&lds_v[(16 * u + n) * 72 + 32 + q * 8]);
            for (int mt = 0; mt < 2; ++mt) {
                o[mt][u] = __builtin_amdgcn_mfma_f32_16x16x32_bf16(ap[mt][0], bv0, o[mt][u], 0, 0, 0);
                o[mt][u] = __builtin_amdgcn_mfma_f32_16x16x32_bf16(ap[mt][1], bv1, o[mt][u], 0, 0, 0);
            }
        }
    }

    // epilogue: write att2 in A-fragment order (pos=i0+mt*16+4q+r, hd=h*64+16u+n)
    for (int mt = 0; mt < 2; ++mt)
        for (int r = 0; r < 4; ++r) {
            float inv = 1.0f / acc_l[mt][r];
            int pt = (i0 >> 4) + mt;
            int np = 4 * q + r;
            for (int u = 0; u < 4; ++u) {
                int kcA = 2 * h + (u >> 1);
                int kq = 2 * (u & 1) + (n >> 3);
                att2[((size_t)((b * 64 + pt) * 16 + kcA) * 512) + (kq * 16 + np) * 8 + (n & 7)] =
                    f2bf(o[mt][u][r] * inv);
            }
        }
}

// ---------------- output projection + residual ----------------
// A = att2 (m=pos), B = w0f (n=c); K=512 in 4 hoisted groups of 4 kcA.
// D row = pos -> float4 stores + float4 residual loads.
__global__ __launch_bounds__(256, 4) void out_gemm(const unsigned short* __restrict__ att2,
                                                   const unsigned short* __restrict__ w0f,
                                                   const float* __restrict__ x,
                                                   float* __restrict__ out) {
    int b = blockIdx.x, ct = blockIdx.y, ptb = blockIdx.z;
    int tid = threadIdx.x, wave = tid >> 6, lane = tid & 63, q = lane >> 4, n = lane & 15;
    int pos0 = ptb * 64 + wave * 16;
    int c0 = ct * 64;
    int pt = ptb * 4 + wave;
    const unsigned short* abase = att2 + (size_t)(b * 64 + pt) * 16 * 512 + lane * 8;
    const unsigned short* wbase = w0f + (size_t)(c0 >> 4) * 16 * 512 + lane * 8;
    floatx4 acc[4];
    for (int s = 0; s < 4; ++s) acc[s] = (floatx4){0.f, 0.f, 0.f, 0.f};
    for (int g = 0; g < 4; ++g) {
        bf16x8 af[4], bfr[4][4];
        for (int k2 = 0; k2 < 4; ++k2) af[k2] = ldfrag(abase + (g * 4 + k2) * 512);
        for (int s = 0; s < 4; ++s)
            for (int k2 = 0; k2 < 4; ++k2)
                bfr[s][k2] = ldfrag(wbase + (s * 16 + g * 4 + k2) * 512);
        for (int k2 = 0; k2 < 4; ++k2)
            for (int s = 0; s < 4; ++s)
                acc[s] = __builtin_amdgcn_mfma_f32_16x16x32_bf16(af[k2], bfr[s][k2], acc[s], 0, 0, 0);
    }
    int p0q = pos0 + 4 * q;
    for (int s = 0; s < 4; ++s) {
        int c = c0 + 16 * s + n;
        size_t idx = ((size_t)b * CIN + c) * SEQ + p0q;
        floatx4 res = *(const floatx4*)&x[idx];
        floatx4 v = acc[s] + res;
        *(floatx4*)&out[idx] = v;
    }
}

// ---------------- launch ----------------
extern "C" void kernel_launch(void* const* d_in, const int* in_sizes, int n_in,
                              void* d_out, int out_size, void* d_ws, size_t ws_size,
                              hipStream_t stream) {
    const float* x  = (const float*)d_in[0];
    const float* Wq = (const float*)d_in[1];
    const float* Wk = (const float*)d_in[2];
    const float* Wv = (const float*)d_in[3];
    const float* R  = (const float*)d_in[4];
    const float* W0 = (const float*)d_in[5];
    float* out = (float*)d_out;

    char* ws = (char*)d_ws;
    size_t off = 0;
    unsigned short* Qt   = (unsigned short*)(ws + off); off += (size_t)NB * NH * SEQ * DKH * 2;
    unsigned short* Kt   = (unsigned short*)(ws + off); off += (size_t)NB * NH * SEQ * DKH * 2;
    unsigned short* Vt   = (unsigned short*)(ws + off); off += (size_t)NB * NH * SEQ * DKH * 2;
    unsigned short* att2 = (unsigned short*)(ws + off); off += (size_t)NB * SEQ * HDIM * 2;
    unsigned short* xt2  = (unsigned short*)(ws + off); off += (size_t)NB * SEQ * CIN * 2;
    unsigned short* w2   = (unsigned short*)(ws + off); off += (size_t)1536 * 128 * 2;
    unsigned short* w0f  = (unsigned short*)(ws + off); off += (size_t)128 * 512 * 2;
    unsigned short* biasC= (unsigned short*)(ws + off); off += (size_t)NH * SEQ * SEQ * 2;
    (void)ws_size; (void)in_sizes; (void)n_in; (void)out_size;

    prep_wb<<<33792, 256, 0, stream>>>(Wq, Wk, Wv, W0, R, w2, w0f, biasC);
    prep_xt<<<dim3(NB, 2, 16), 256, 0, stream>>>(x, xt2);
    qkv_gemm<<<dim3(NB, 24, 16), 256, 0, stream>>>(xt2, w2, Qt, Kt, Vt);
    attn_kernel<<<NB * NH * 8, 256, 0, stream>>>(Qt, Kt, Vt, biasC, att2);
    out_gemm<<<dim3(NB, 2, 16), 256, 0, stream>>>(att2, w0f, x, out);
}